// Round 3
// baseline (549.925 us; speedup 1.0000x reference)
//
#include <hip/hip_runtime.h>
#include <stdint.h>

#define ALPHA 0.2f
#define EPSV  1e-5f
#define NEGV  -9e15f

typedef unsigned short u16;
typedef unsigned int   u32;
typedef unsigned long long u64;
typedef __bf16 bf16x8 __attribute__((ext_vector_type(8)));
typedef float  f32x4  __attribute__((ext_vector_type(4)));

#define NB 8
#define NS 64
#define NN 256
#define NF 16
#define NH 16
#define NC 4096     // N*H
#define NK 12288    // NC*3
#define NP 512      // B*S (GEMM M / column count)

__device__ __forceinline__ u16 f2b(float f){
  u32 u = __float_as_uint(f);
  u32 r = u + 0x7fffu + ((u>>16)&1u);   // round-nearest-even
  return (u16)(r>>16);
}
__device__ __forceinline__ u32 pack2(float a, float b){ return (u32)f2b(a) | ((u32)f2b(b)<<16); }

// ---------------- k1: Wh = x@W, f1 = Wh.a1, f2 = Wh.a2 -------------------
__global__ __launch_bounds__(256) void k_wh(
    const float* __restrict__ x, const float* __restrict__ W,
    const float* __restrict__ a1, const float* __restrict__ a2,
    float* __restrict__ Wh, float* __restrict__ f1o, float* __restrict__ f2o){
  __shared__ __align__(16) float Ws[NF][NH];
  __shared__ float a1s[NH], a2s[NH];
  int t = threadIdx.x, bs = blockIdx.x;
  Ws[t>>4][t&15] = W[t];
  if(t<NH){ a1s[t]=a1[t]; a2s[t]=a2[t]; }
  __syncthreads();
  const float* xp = x + ((size_t)bs*NN + t)*NF;
  float xr[16];
  #pragma unroll
  for(int g=0;g<4;g++) *(f32x4*)&xr[g*4] = ((const f32x4*)xp)[g];
  float wh[16];
  #pragma unroll
  for(int h=0;h<16;h++) wh[h]=0.f;
  #pragma unroll
  for(int f=0;f<16;f++){
    float xf = xr[f];
    #pragma unroll
    for(int h=0;h<16;h++) wh[h] = fmaf(xf, Ws[f][h], wh[h]);
  }
  float s1=0.f, s2=0.f;
  #pragma unroll
  for(int h=0;h<16;h++){ s1=fmaf(wh[h],a1s[h],s1); s2=fmaf(wh[h],a2s[h],s2); }
  float* whp = Wh + ((size_t)bs*NN + t)*NH;
  #pragma unroll
  for(int g=0;g<4;g++) ((f32x4*)whp)[g] = *(f32x4*)&wh[g*4];
  f1o[bs*NN+t]=s1; f2o[bs*NN+t]=s2;
}

// ---------------- k_adj: adjacency -> 256x256 bitmask ---------------------
__global__ __launch_bounds__(256) void k_adj(const float* __restrict__ adj,
                                             u64* __restrict__ am){
  int i = threadIdx.x;
  u64 m[4] = {0,0,0,0};
  for(int j=0;j<NN;j++){
    if(adj[i*NN+j] > 0.f) m[j>>6] |= (1ull << (j&63));
  }
  #pragma unroll
  for(int w=0;w<4;w++) am[i*4+w] = m[w];
}

// ---------------- k_cw: conv_w fp32 -> bf16 (flat 50.3M elems) ------------
__global__ __launch_bounds__(256) void k_cw(const float* __restrict__ cw,
                                            u16* __restrict__ bw){
  size_t i = ((size_t)blockIdx.x*256 + threadIdx.x)*8;
  f32x4 f0 = ((const f32x4*)(cw+i))[0];
  f32x4 f1v = ((const f32x4*)(cw+i))[1];
  uint4 o;
  o.x = pack2(f0[0],f0[1]); o.y = pack2(f0[2],f0[3]);
  o.z = pack2(f1v[0],f1v[1]); o.w = pack2(f1v[2],f1v[3]);
  *(uint4*)(bw+i) = o;
}

// ---- k2: masked-softmax attention + spatial = attn@Wh, scatter into Bt ---
// Bt[col = b*64+cs][ci*3+k] = t_padded[b][ci][cs+k]  (512 x 12288 bf16)
__global__ __launch_bounds__(256) void k_attn(
    const float* __restrict__ Wh, const float* __restrict__ f1,
    const float* __restrict__ f2, const u64* __restrict__ am,
    u16* __restrict__ Bt){
  __shared__ __align__(16) float Whs[NN][NH];
  __shared__ float f2s[NN];
  int t = threadIdx.x, bs = blockIdx.x;
  int b = bs>>6, s = bs&63;
  const float* wrow = Wh + ((size_t)bs*NN + t)*NH;
  #pragma unroll
  for(int g=0;g<4;g++) ((f32x4*)Whs[t])[g] = ((const f32x4*)wrow)[g];
  f2s[t] = f2[bs*NN + t];
  float fi = f1[bs*NN + t];
  u64 mg[4];
  #pragma unroll
  for(int g=0;g<4;g++) mg[g] = am[t*4+g];
  __syncthreads();

  float mx = NEGV;
  #pragma unroll
  for(int g=0;g<4;g++){
    u64 mm = mg[g];
    for(int jj=0;jj<64;jj++){
      float e = fi + f2s[g*64+jj];
      e = e > 0.f ? e : ALPHA*e;
      e = ((mm>>jj)&1ull) ? e : NEGV;
      mx = fmaxf(mx, e);
    }
  }
  float den = 0.f;
  f32x4 a0={0,0,0,0}, a1v={0,0,0,0}, a2v={0,0,0,0}, a3v={0,0,0,0};
  #pragma unroll
  for(int g=0;g<4;g++){
    u64 mm = mg[g];
    for(int jj=0;jj<64;jj++){
      int j = g*64+jj;
      float e = fi + f2s[j];
      e = e > 0.f ? e : ALPHA*e;
      e = ((mm>>jj)&1ull) ? e : NEGV;
      float p = __expf(e - mx);
      den += p;
      const f32x4* wr = (const f32x4*)Whs[j];
      a0 += wr[0]*p; a1v += wr[1]*p; a2v += wr[2]*p; a3v += wr[3]*p;
    }
  }
  float inv = 1.f/fmaxf(den, 1e-30f);
  float vals[16];
  *(f32x4*)&vals[0]  = a0*inv;  *(f32x4*)&vals[4]  = a1v*inv;
  *(f32x4*)&vals[8]  = a2v*inv; *(f32x4*)&vals[12] = a3v*inv;

  // scatter: value at source position s contributes to rows cs = s+1-k
  #pragma unroll
  for(int k=0;k<3;k++){
    int cs = s + 1 - k;
    if(cs >= 0 && cs < NS){
      size_t base = ((size_t)(b*NS+cs))*NK + (size_t)t*48 + k;
      #pragma unroll
      for(int h=0;h<16;h++) Bt[base + h*3] = f2b(vals[h]);
    }
  }
  if(s == 0){            // zero pad entries: row 0, tap 0
    size_t base = ((size_t)(b*NS))*NK + (size_t)t*48;
    #pragma unroll
    for(int h=0;h<16;h++) Bt[base + h*3] = 0;
  }
  if(s == NS-1){         // zero pad entries: row 63, tap 2
    size_t base = ((size_t)(b*NS+NS-1))*NK + (size_t)t*48 + 2;
    #pragma unroll
    for(int h=0;h<16;h++) Bt[base + h*3] = 0;
  }
}

// ------- k3: GEMM  yp[col][co] = sum_K Bt[col][K] * Bw[co][K] ------------
// M=512 (cols), N=4096 (co), K=12288. 128x128 tile, BK=32, split-K over z.
__global__ __launch_bounds__(256) void k_gemm(
    const u16* __restrict__ Abt, const u16* __restrict__ Bw,
    float* __restrict__ yp, int kchunk){
  __shared__ __align__(16) u16 As[128*32];
  __shared__ __align__(16) u16 Bs[128*32];
  int t = threadIdx.x;
  int m0 = blockIdx.x*128, n0 = blockIdx.y*128;
  int kbeg = blockIdx.z*kchunk;
  f32x4 acc[4][4];
  #pragma unroll
  for(int i=0;i<4;i++)
    #pragma unroll
    for(int j=0;j<4;j++) acc[i][j] = (f32x4){0,0,0,0};

  int l = t&63, w = t>>6;
  int wm = (w&1)*64, wn = (w>>1)*64;
  int q = l>>4, r16 = l&15;

  int c0 = t, c1 = t+256;
  const u16* ga0 = Abt + (size_t)(m0 + (c0>>2))*NK + (c0&3)*8;
  const u16* ga1 = Abt + (size_t)(m0 + (c1>>2))*NK + (c1&3)*8;
  const u16* gb0 = Bw  + (size_t)(n0 + (c0>>2))*NK + (c0&3)*8;
  const u16* gb1 = Bw  + (size_t)(n0 + (c1>>2))*NK + (c1&3)*8;
  u16* la0 = As + c0*8; u16* la1 = As + c1*8;
  u16* lb0 = Bs + c0*8; u16* lb1 = Bs + c1*8;

  for(int kk=0; kk<kchunk; kk+=32){
    int k0 = kbeg + kk;
    uint4 va0 = *(const uint4*)(ga0 + k0);
    uint4 va1 = *(const uint4*)(ga1 + k0);
    uint4 vb0 = *(const uint4*)(gb0 + k0);
    uint4 vb1 = *(const uint4*)(gb1 + k0);
    __syncthreads();                       // previous iter's LDS reads done
    *(uint4*)la0 = va0;
    *(uint4*)la1 = va1;
    *(uint4*)lb0 = vb0;
    *(uint4*)lb1 = vb1;
    __syncthreads();                       // staging visible to all waves
    bf16x8 af[4], bfr[4];
    #pragma unroll
    for(int mt=0;mt<4;mt++) af[mt]  = *(const bf16x8*)(As + (wm+mt*16+r16)*32 + q*8);
    #pragma unroll
    for(int nt=0;nt<4;nt++) bfr[nt] = *(const bf16x8*)(Bs + (wn+nt*16+r16)*32 + q*8);
    #pragma unroll
    for(int mt=0;mt<4;mt++)
      #pragma unroll
      for(int nt=0;nt<4;nt++)
        acc[mt][nt] = __builtin_amdgcn_mfma_f32_16x16x32_bf16(af[mt], bfr[nt], acc[mt][nt], 0,0,0);
  }
  float* op = yp + (size_t)blockIdx.z*NP*NC;
  #pragma unroll
  for(int mt=0;mt<4;mt++)
    #pragma unroll
    for(int nt=0;nt<4;nt++)
      #pragma unroll
      for(int rr=0;rr<4;rr++){
        int m = m0 + wm + mt*16 + q*4 + rr;   // C/D: row = quad*4+reg
        int n = n0 + wn + nt*16 + r16;        //      col = lane&15
        op[(size_t)m*NC + n] = acc[mt][nt][rr];
      }
}

// ------ k4: sum split-K, conv_b + BN + relu + residual + LayerNorm -------
__global__ __launch_bounds__(256) void k_post(
    const float* __restrict__ yp, int nparts,
    const float* __restrict__ x,
    const float* __restrict__ cb, const float* __restrict__ bg,
    const float* __restrict__ bb, const float* __restrict__ bm,
    const float* __restrict__ bv, const float* __restrict__ lg,
    const float* __restrict__ lb, float* __restrict__ out){
  int n = threadIdx.x, bs = blockIdx.x;   // bs == col == b*64+s
  float v[16];
  #pragma unroll
  for(int g=0;g<4;g++){
    f32x4 sum = {0,0,0,0};
    for(int p=0;p<nparts;p++)
      sum += ((const f32x4*)(yp + (size_t)p*NP*NC + (size_t)bs*NC + n*16))[g];
    *(f32x4*)&v[g*4] = sum;
  }
  const float* xp = x + ((size_t)bs*NN + n)*NH;
  float xr[16];
  #pragma unroll
  for(int g=0;g<4;g++) *(f32x4*)&xr[g*4] = ((const f32x4*)xp)[g];

  float mu = 0.f;
  #pragma unroll
  for(int h=0;h<16;h++){
    int co = n*16 + h;
    float t1 = v[h] + cb[co];
    t1 = (t1 - bm[co]) * (1.f/sqrtf(bv[co] + EPSV));
    t1 = t1 * bg[co] + bb[co];
    t1 = fmaxf(t1, 0.f);
    t1 += xr[h];
    v[h] = t1; mu += t1;
  }
  mu *= (1.f/16.f);
  float var = 0.f;
  #pragma unroll
  for(int h=0;h<16;h++){ float d = v[h]-mu; var = fmaf(d,d,var); }
  var *= (1.f/16.f);
  float rs = 1.f/sqrtf(var + EPSV);
  float* op = out + ((size_t)bs*NN + n)*NH;
  #pragma unroll
  for(int h=0;h<16;h++) op[h] = (v[h]-mu)*rs*lg[h] + lb[h];
}

extern "C" void kernel_launch(void* const* d_in, const int* in_sizes, int n_in,
                              void* d_out, int out_size, void* d_ws, size_t ws_size,
                              hipStream_t stream){
  const float* x   = (const float*)d_in[0];
  const float* adj = (const float*)d_in[1];
  const float* W   = (const float*)d_in[2];
  const float* a1  = (const float*)d_in[3];
  const float* a2  = (const float*)d_in[4];
  const float* cw  = (const float*)d_in[5];
  const float* cb  = (const float*)d_in[6];
  const float* bg  = (const float*)d_in[7];
  const float* bb  = (const float*)d_in[8];
  const float* bm  = (const float*)d_in[9];
  const float* bv  = (const float*)d_in[10];
  const float* lg  = (const float*)d_in[11];
  const float* lb  = (const float*)d_in[12];
  float* out = (float*)d_out;

  char* ws = (char*)d_ws;
  const size_t WH_OFF = 0;
  const size_t F1_OFF = WH_OFF + (size_t)NP*NN*NH*4;   // 8 MB
  const size_t F2_OFF = F1_OFF + (size_t)NP*NN*4;
  const size_t AM_OFF = F2_OFF + (size_t)NP*NN*4;
  const size_t BT_OFF = AM_OFF + (size_t)NN*4*8;
  const size_t BW_OFF = BT_OFF + (size_t)NP*NK*2;      // Bt: 12.6 MB
  const size_t YP_OFF = BW_OFF + (size_t)NC*NK*2;      // Bw: 100.7 MB
  const size_t ypb    = (size_t)NP*NC*4;               // 8 MB per split
  int P = 1;
  if(ws_size >= YP_OFF + 4*ypb)      P = 4;
  else if(ws_size >= YP_OFF + 2*ypb) P = 2;

  float* Wh  = (float*)(ws + WH_OFF);
  float* f1  = (float*)(ws + F1_OFF);
  float* f2  = (float*)(ws + F2_OFF);
  u64*   am  = (u64*)  (ws + AM_OFF);
  u16*   Bt  = (u16*)  (ws + BT_OFF);
  u16*   Bw  = (u16*)  (ws + BW_OFF);
  float* yp  = (float*)(ws + YP_OFF);

  hipLaunchKernelGGL(k_wh,   dim3(NP),        dim3(256), 0, stream, x,W,a1,a2,Wh,f1,f2);
  hipLaunchKernelGGL(k_adj,  dim3(1),         dim3(256), 0, stream, adj, am);
  hipLaunchKernelGGL(k_cw,   dim3(NC*NK/(256*8)), dim3(256), 0, stream, cw, Bw);
  hipLaunchKernelGGL(k_attn, dim3(NP),        dim3(256), 0, stream, Wh,f1,f2,am,Bt);
  hipLaunchKernelGGL(k_gemm, dim3(4,32,P),    dim3(256), 0, stream, Bt, Bw, yp, NK/P);
  hipLaunchKernelGGL(k_post, dim3(NP),        dim3(256), 0, stream, yp,P,x,cb,bg,bb,bm,bv,lg,lb,out);
}

// Round 4
// 522.878 us; speedup vs baseline: 1.0517x; 1.0517x over previous
//
#include <hip/hip_runtime.h>
#include <stdint.h>

#define ALPHA 0.2f
#define EPSV  1e-5f
#define NEGV  -9e15f

typedef unsigned short u16;
typedef unsigned int   u32;
typedef unsigned long long u64;
typedef __bf16 bf16x8 __attribute__((ext_vector_type(8)));
typedef float  f32x4  __attribute__((ext_vector_type(4)));

#define NB 8
#define NS 64
#define NN 256
#define NF 16
#define NH 16
#define NC 4096     // N*H
#define NK 12288    // NC*3
#define NP 512      // B*S (GEMM M / column count)

__device__ __forceinline__ u16 f2b(float f){
  u32 u = __float_as_uint(f);
  u32 r = u + 0x7fffu + ((u>>16)&1u);   // round-nearest-even
  return (u16)(r>>16);
}
__device__ __forceinline__ u32 pack2(float a, float b){ return (u32)f2b(a) | ((u32)f2b(b)<<16); }
__device__ __forceinline__ void gld16(void* lds, const void* g){
  __builtin_amdgcn_global_load_lds((const __attribute__((address_space(1))) u32*)g,
                                   (__attribute__((address_space(3))) u32*)lds, 16, 0, 0);
}

// ---------------- k1: Wh = x@W, f1 = Wh.a1, f2 = Wh.a2 -------------------
__global__ __launch_bounds__(256) void k_wh(
    const float* __restrict__ x, const float* __restrict__ W,
    const float* __restrict__ a1, const float* __restrict__ a2,
    float* __restrict__ Wh, float* __restrict__ f1o, float* __restrict__ f2o){
  __shared__ __align__(16) float Ws[NF][NH];
  __shared__ float a1s[NH], a2s[NH];
  int t = threadIdx.x, bs = blockIdx.x;
  Ws[t>>4][t&15] = W[t];
  if(t<NH){ a1s[t]=a1[t]; a2s[t]=a2[t]; }
  __syncthreads();
  const float* xp = x + ((size_t)bs*NN + t)*NF;
  float xr[16];
  #pragma unroll
  for(int g=0;g<4;g++) *(f32x4*)&xr[g*4] = ((const f32x4*)xp)[g];
  float wh[16];
  #pragma unroll
  for(int h=0;h<16;h++) wh[h]=0.f;
  #pragma unroll
  for(int f=0;f<16;f++){
    float xf = xr[f];
    #pragma unroll
    for(int h=0;h<16;h++) wh[h] = fmaf(xf, Ws[f][h], wh[h]);
  }
  float s1=0.f, s2=0.f;
  #pragma unroll
  for(int h=0;h<16;h++){ s1=fmaf(wh[h],a1s[h],s1); s2=fmaf(wh[h],a2s[h],s2); }
  float* whp = Wh + ((size_t)bs*NN + t)*NH;
  #pragma unroll
  for(int g=0;g<4;g++) ((f32x4*)whp)[g] = *(f32x4*)&wh[g*4];
  f1o[bs*NN+t]=s1; f2o[bs*NN+t]=s2;
}

// ------- k_adj: adjacency -> bitmask, coalesced + ballot (64 blocks) ------
__global__ __launch_bounds__(256) void k_adj(const float* __restrict__ adj,
                                             u64* __restrict__ am){
  int w = threadIdx.x>>6, l = threadIdx.x&63;
  int row = blockIdx.x*4 + w;
  #pragma unroll
  for(int g=0;g<4;g++){
    float v = adj[(size_t)row*NN + g*64 + l];
    u64 m = __ballot(v > 0.f);
    if(l==0) am[row*4+g] = m;
  }
}

// ---------------- k_cw: conv_w fp32 -> bf16 (flat 50.3M elems) ------------
__global__ __launch_bounds__(256) void k_cw(const float* __restrict__ cw,
                                            u16* __restrict__ bw){
  size_t i = ((size_t)blockIdx.x*256 + threadIdx.x)*8;
  f32x4 f0 = ((const f32x4*)(cw+i))[0];
  f32x4 f1v = ((const f32x4*)(cw+i))[1];
  uint4 o;
  o.x = pack2(f0[0],f0[1]); o.y = pack2(f0[2],f0[3]);
  o.z = pack2(f1v[0],f1v[1]); o.w = pack2(f1v[2],f1v[3]);
  *(uint4*)(bw+i) = o;
}

// ---- k2: single-pass masked softmax + spatial = attn@Wh -> Bt (bf16) ----
// No max-subtraction: |e| <~ 20 so exp() is safe in fp32; masked lanes get
// p = 0 exactly. Bt[col = b*64+cs][ci*3+k] = t_padded[b][ci][cs+k].
__global__ __launch_bounds__(256) void k_attn(
    const float* __restrict__ Wh, const float* __restrict__ f1,
    const float* __restrict__ f2, const u64* __restrict__ am,
    u16* __restrict__ Bt){
  __shared__ __align__(16) float Whs[NN][NH];
  __shared__ float f2s[NN];
  int t = threadIdx.x, bs = blockIdx.x;
  int b = bs>>6, s = bs&63;
  const float* wrow = Wh + ((size_t)bs*NN + t)*NH;
  #pragma unroll
  for(int g=0;g<4;g++) ((f32x4*)Whs[t])[g] = ((const f32x4*)wrow)[g];
  f2s[t] = f2[bs*NN + t];
  float fi = f1[bs*NN + t];
  u64 mg[4];
  #pragma unroll
  for(int g=0;g<4;g++) mg[g] = am[t*4+g];
  __syncthreads();

  float den = 0.f;
  f32x4 a0={0,0,0,0}, a1v={0,0,0,0}, a2v={0,0,0,0}, a3v={0,0,0,0};
  #pragma unroll
  for(int g=0;g<4;g++){
    u64 mm = mg[g];
    for(int jj=0;jj<64;jj++){
      int j = g*64+jj;
      float e = fi + f2s[j];
      e = e > 0.f ? e : ALPHA*e;
      float p = ((mm>>jj)&1ull) ? __expf(e) : 0.f;
      den += p;
      const f32x4* wr = (const f32x4*)Whs[j];
      a0 += wr[0]*p; a1v += wr[1]*p; a2v += wr[2]*p; a3v += wr[3]*p;
    }
  }
  float inv = 1.f/fmaxf(den, 1e-30f);
  float vals[16];
  *(f32x4*)&vals[0]  = a0*inv;  *(f32x4*)&vals[4]  = a1v*inv;
  *(f32x4*)&vals[8]  = a2v*inv; *(f32x4*)&vals[12] = a3v*inv;

  // scatter: value at source position s contributes to rows cs = s+1-k
  #pragma unroll
  for(int k=0;k<3;k++){
    int cs = s + 1 - k;
    if(cs >= 0 && cs < NS){
      size_t base = ((size_t)(b*NS+cs))*NK + (size_t)t*48 + k;
      #pragma unroll
      for(int h=0;h<16;h++) Bt[base + h*3] = f2b(vals[h]);
    }
  }
  if(s == 0){            // zero pad entries: row 0, tap 0
    size_t base = ((size_t)(b*NS))*NK + (size_t)t*48;
    #pragma unroll
    for(int h=0;h<16;h++) Bt[base + h*3] = 0;
  }
  if(s == NS-1){         // zero pad entries: row 63, tap 2
    size_t base = ((size_t)(b*NS+NS-1))*NK + (size_t)t*48 + 2;
    #pragma unroll
    for(int h=0;h<16;h++) Bt[base + h*3] = 0;
  }
}

// ------- k3: GEMM  yp[col][co] = sum_K Bt[col][K] * Bw[co][K] ------------
// M=512, N=4096, K=12288. 128x128 tile, BK=32, split-K over blockIdx.y.
// global_load_lds width-16 staging (dest = wave-uniform base + lane*16:
// lane c -> As + c*16B, contiguous per wave -> legal). XCD swizzle: the 4
// m-blocks sharing one B-tile get linear ids congruent mod 8 -> same XCD L2.
__global__ __launch_bounds__(256) void k_gemm(
    const u16* __restrict__ Abt, const u16* __restrict__ Bw,
    float* __restrict__ yp, int kchunk){
  __shared__ __align__(16) u16 As[128*32];
  __shared__ __align__(16) u16 Bs[128*32];
  int t = threadIdx.x;
  int id = blockIdx.x;               // 0..127
  int xr_ = id & 7, q0 = id >> 3;    // xcd residue, remainder
  int mI = q0 & 3, nhi = q0 >> 2;    // m in [0,4), nhi in [0,4)
  int m0 = mI*128, n0 = (nhi*8 + xr_)*128;
  int kbeg = blockIdx.y*kchunk;
  f32x4 acc[4][4];
  #pragma unroll
  for(int i=0;i<4;i++)
    #pragma unroll
    for(int j=0;j<4;j++) acc[i][j] = (f32x4){0,0,0,0};

  int l = t&63, w = t>>6;
  int wm = (w&1)*64, wn = (w>>1)*64;
  int q = l>>4, r16 = l&15;

  int c0 = t, c1 = t+256;
  const u16* ga0 = Abt + (size_t)(m0 + (c0>>2))*NK + (c0&3)*8;
  const u16* ga1 = Abt + (size_t)(m0 + (c1>>2))*NK + (c1&3)*8;
  const u16* gb0 = Bw  + (size_t)(n0 + (c0>>2))*NK + (c0&3)*8;
  const u16* gb1 = Bw  + (size_t)(n0 + (c1>>2))*NK + (c1&3)*8;
  u16* la0 = As + c0*8; u16* la1 = As + c1*8;
  u16* lb0 = Bs + c0*8; u16* lb1 = Bs + c1*8;

  for(int kk=0; kk<kchunk; kk+=32){
    int k0 = kbeg + kk;
    __syncthreads();                       // prior iter's LDS reads done
    gld16(la0, ga0 + k0);
    gld16(la1, ga1 + k0);
    gld16(lb0, gb0 + k0);
    gld16(lb1, gb1 + k0);
    __syncthreads();                       // drains vmcnt -> staging visible
    bf16x8 af[4], bfr[4];
    #pragma unroll
    for(int mt=0;mt<4;mt++) af[mt]  = *(const bf16x8*)(As + (wm+mt*16+r16)*32 + q*8);
    #pragma unroll
    for(int nt=0;nt<4;nt++) bfr[nt] = *(const bf16x8*)(Bs + (wn+nt*16+r16)*32 + q*8);
    #pragma unroll
    for(int mt=0;mt<4;mt++)
      #pragma unroll
      for(int nt=0;nt<4;nt++)
        acc[mt][nt] = __builtin_amdgcn_mfma_f32_16x16x32_bf16(af[mt], bfr[nt], acc[mt][nt], 0,0,0);
  }
  float* op = yp + (size_t)blockIdx.y*NP*NC;
  #pragma unroll
  for(int mt=0;mt<4;mt++)
    #pragma unroll
    for(int nt=0;nt<4;nt++)
      #pragma unroll
      for(int rr=0;rr<4;rr++){
        int m = m0 + wm + mt*16 + q*4 + rr;   // C/D: row = quad*4+reg
        int n = n0 + wn + nt*16 + r16;        //      col = lane&15
        op[(size_t)m*NC + n] = acc[mt][nt][rr];
      }
}

// ------ k4: sum split-K, conv_b + BN + relu + residual + LayerNorm -------
__global__ __launch_bounds__(256) void k_post(
    const float* __restrict__ yp, int nparts,
    const float* __restrict__ x,
    const float* __restrict__ cb, const float* __restrict__ bg,
    const float* __restrict__ bb, const float* __restrict__ bm,
    const float* __restrict__ bv, const float* __restrict__ lg,
    const float* __restrict__ lb, float* __restrict__ out){
  int n = threadIdx.x, bs = blockIdx.x;   // bs == col == b*64+s
  float v[16];
  #pragma unroll
  for(int g=0;g<4;g++){
    f32x4 sum = {0,0,0,0};
    for(int p=0;p<nparts;p++)
      sum += ((const f32x4*)(yp + (size_t)p*NP*NC + (size_t)bs*NC + n*16))[g];
    *(f32x4*)&v[g*4] = sum;
  }
  const float* xp = x + ((size_t)bs*NN + n)*NH;
  float xr[16];
  #pragma unroll
  for(int g=0;g<4;g++) *(f32x4*)&xr[g*4] = ((const f32x4*)xp)[g];

  float mu = 0.f;
  #pragma unroll
  for(int h=0;h<16;h++){
    int co = n*16 + h;
    float t1 = v[h] + cb[co];
    t1 = (t1 - bm[co]) * (1.f/sqrtf(bv[co] + EPSV));
    t1 = t1 * bg[co] + bb[co];
    t1 = fmaxf(t1, 0.f);
    t1 += xr[h];
    v[h] = t1; mu += t1;
  }
  mu *= (1.f/16.f);
  float var = 0.f;
  #pragma unroll
  for(int h=0;h<16;h++){ float d = v[h]-mu; var = fmaf(d,d,var); }
  var *= (1.f/16.f);
  float rs = 1.f/sqrtf(var + EPSV);
  float* op = out + ((size_t)bs*NN + n)*NH;
  #pragma unroll
  for(int h=0;h<16;h++) op[h] = (v[h]-mu)*rs*lg[h] + lb[h];
}

extern "C" void kernel_launch(void* const* d_in, const int* in_sizes, int n_in,
                              void* d_out, int out_size, void* d_ws, size_t ws_size,
                              hipStream_t stream){
  const float* x   = (const float*)d_in[0];
  const float* adj = (const float*)d_in[1];
  const float* W   = (const float*)d_in[2];
  const float* a1  = (const float*)d_in[3];
  const float* a2  = (const float*)d_in[4];
  const float* cw  = (const float*)d_in[5];
  const float* cb  = (const float*)d_in[6];
  const float* bg  = (const float*)d_in[7];
  const float* bb  = (const float*)d_in[8];
  const float* bm  = (const float*)d_in[9];
  const float* bv  = (const float*)d_in[10];
  const float* lg  = (const float*)d_in[11];
  const float* lb  = (const float*)d_in[12];
  float* out = (float*)d_out;

  char* ws = (char*)d_ws;
  const size_t WH_OFF = 0;
  const size_t F1_OFF = WH_OFF + (size_t)NP*NN*NH*4;   // 8 MB
  const size_t F2_OFF = F1_OFF + (size_t)NP*NN*4;
  const size_t AM_OFF = F2_OFF + (size_t)NP*NN*4;
  const size_t BT_OFF = AM_OFF + (size_t)NN*4*8;
  const size_t BW_OFF = BT_OFF + (size_t)NP*NK*2;      // Bt: 12.6 MB
  const size_t YP_OFF = BW_OFF + (size_t)NC*NK*2;      // Bw: 100.7 MB
  const size_t ypb    = (size_t)NP*NC*4;               // 8 MB per split
  int P = 1;
  if(ws_size >= YP_OFF + 8*ypb)      P = 8;
  else if(ws_size >= YP_OFF + 4*ypb) P = 4;
  else if(ws_size >= YP_OFF + 2*ypb) P = 2;

  float* Wh  = (float*)(ws + WH_OFF);
  float* f1  = (float*)(ws + F1_OFF);
  float* f2  = (float*)(ws + F2_OFF);
  u64*   am  = (u64*)  (ws + AM_OFF);
  u16*   Bt  = (u16*)  (ws + BT_OFF);
  u16*   Bw  = (u16*)  (ws + BW_OFF);
  float* yp  = (float*)(ws + YP_OFF);

  hipLaunchKernelGGL(k_wh,   dim3(NP),        dim3(256), 0, stream, x,W,a1,a2,Wh,f1,f2);
  hipLaunchKernelGGL(k_adj,  dim3(64),        dim3(256), 0, stream, adj, am);
  hipLaunchKernelGGL(k_cw,   dim3(NC*NK/(256*8)), dim3(256), 0, stream, cw, Bw);
  hipLaunchKernelGGL(k_attn, dim3(NP),        dim3(256), 0, stream, Wh,f1,f2,am,Bt);
  hipLaunchKernelGGL(k_gemm, dim3(128,P),     dim3(256), 0, stream, Bt, Bw, yp, NK/P);
  hipLaunchKernelGGL(k_post, dim3(NP),        dim3(256), 0, stream, yp,P,x,cb,bg,bb,bm,bv,lg,lb,out);
}

// Round 5
// 501.214 us; speedup vs baseline: 1.0972x; 1.0432x over previous
//
#include <hip/hip_runtime.h>
#include <stdint.h>

#define ALPHA 0.2f
#define EPSV  1e-5f

typedef unsigned short u16;
typedef unsigned int   u32;
typedef unsigned long long u64;
typedef __bf16 bf16x8 __attribute__((ext_vector_type(8)));
typedef float  f32x4  __attribute__((ext_vector_type(4)));

#define NB 8
#define NS 64
#define NN 256
#define NF 16
#define NH 16
#define NC 4096     // N*H
#define NK 12288    // NC*3
#define NP 512      // B*S (GEMM M / column count)

__device__ __forceinline__ u16 f2b(float f){
  u32 u = __float_as_uint(f);
  u32 r = u + 0x7fffu + ((u>>16)&1u);   // round-nearest-even
  return (u16)(r>>16);
}
__device__ __forceinline__ u32 pack2(float a, float b){ return (u32)f2b(a) | ((u32)f2b(b)<<16); }
__device__ __forceinline__ void gld16(void* lds, const void* g){
  __builtin_amdgcn_global_load_lds((const __attribute__((address_space(1))) u32*)g,
                                   (__attribute__((address_space(3))) u32*)lds, 16, 0, 0);
}

// ------- k_adj: adjacency -> bitmask, coalesced + ballot (64 blocks) ------
__global__ __launch_bounds__(256) void k_adj(const float* __restrict__ adj,
                                             u64* __restrict__ am){
  int w = threadIdx.x>>6, l = threadIdx.x&63;
  int row = blockIdx.x*4 + w;
  #pragma unroll
  for(int g=0;g<4;g++){
    float v = adj[(size_t)row*NN + g*64 + l];
    u64 m = __ballot(v > 0.f);
    if(l==0) am[row*4+g] = m;
  }
}

// ---------------- k_cw: conv_w fp32 -> bf16 (flat 50.3M elems) ------------
__global__ __launch_bounds__(256) void k_cw(const float* __restrict__ cw,
                                            u16* __restrict__ bw){
  size_t i = ((size_t)blockIdx.x*256 + threadIdx.x)*8;
  f32x4 f0 = ((const f32x4*)(cw+i))[0];
  f32x4 f1v = ((const f32x4*)(cw+i))[1];
  uint4 o;
  o.x = pack2(f0[0],f0[1]); o.y = pack2(f0[2],f0[3]);
  o.z = pack2(f1v[0],f1v[1]); o.w = pack2(f1v[2],f1v[3]);
  *(uint4*)(bw+i) = o;
}

// --- k_attn (merged Wh + attention): per block bs, compute Wh rows into
// LDS, then single-pass masked softmax + spatial = attn@Wh -> Bt (bf16).
// Bt[col = b*64+cs][ci*3+k] = t_padded[b][ci][cs+k]  (512 x 12288 bf16)
__global__ __launch_bounds__(256) void k_attn(
    const float* __restrict__ x, const float* __restrict__ W,
    const float* __restrict__ a1, const float* __restrict__ a2,
    const u64* __restrict__ am, u16* __restrict__ Bt){
  __shared__ __align__(16) float Ws[NF][NH];
  __shared__ float a1s[NH], a2s[NH];
  __shared__ __align__(16) float Whs[NN][NH];
  __shared__ float f2s[NN];
  int t = threadIdx.x, bs = blockIdx.x;
  int b = bs>>6, s = bs&63;
  Ws[t>>4][t&15] = W[t];
  if(t<NH){ a1s[t]=a1[t]; a2s[t]=a2[t]; }
  u64 mg[4];
  #pragma unroll
  for(int g=0;g<4;g++) mg[g] = am[t*4+g];
  __syncthreads();

  const float* xp = x + ((size_t)bs*NN + t)*NF;
  float xr[16];
  #pragma unroll
  for(int g=0;g<4;g++) *(f32x4*)&xr[g*4] = ((const f32x4*)xp)[g];
  float wh[16];
  #pragma unroll
  for(int h=0;h<16;h++) wh[h]=0.f;
  #pragma unroll
  for(int f=0;f<16;f++){
    float xf = xr[f];
    #pragma unroll
    for(int h=0;h<16;h++) wh[h] = fmaf(xf, Ws[f][h], wh[h]);
  }
  float fi=0.f, s2=0.f;
  #pragma unroll
  for(int h=0;h<16;h++){ fi=fmaf(wh[h],a1s[h],fi); s2=fmaf(wh[h],a2s[h],s2); }
  #pragma unroll
  for(int g=0;g<4;g++) ((f32x4*)Whs[t])[g] = *(f32x4*)&wh[g*4];
  f2s[t] = s2;
  __syncthreads();

  // single-pass masked softmax (no max-subtract: |e| small in fp32)
  float den = 0.f;
  f32x4 a0={0,0,0,0}, a1v={0,0,0,0}, a2v={0,0,0,0}, a3v={0,0,0,0};
  #pragma unroll
  for(int g=0;g<4;g++){
    u64 mm = mg[g];
    for(int jj=0;jj<64;jj++){
      int j = g*64+jj;
      float e = fi + f2s[j];
      e = e > 0.f ? e : ALPHA*e;
      float p = ((mm>>jj)&1ull) ? __expf(e) : 0.f;
      den += p;
      const f32x4* wr = (const f32x4*)Whs[j];
      a0 += wr[0]*p; a1v += wr[1]*p; a2v += wr[2]*p; a3v += wr[3]*p;
    }
  }
  float inv = 1.f/fmaxf(den, 1e-30f);
  float vals[16];
  *(f32x4*)&vals[0]  = a0*inv;  *(f32x4*)&vals[4]  = a1v*inv;
  *(f32x4*)&vals[8]  = a2v*inv; *(f32x4*)&vals[12] = a3v*inv;

  // scatter: value at source position s contributes to rows cs = s+1-k
  #pragma unroll
  for(int k=0;k<3;k++){
    int cs = s + 1 - k;
    if(cs >= 0 && cs < NS){
      size_t base = ((size_t)(b*NS+cs))*NK + (size_t)t*48 + k;
      #pragma unroll
      for(int h=0;h<16;h++) Bt[base + h*3] = f2b(vals[h]);
    }
  }
  if(s == 0){            // zero pad entries: row 0, tap 0
    size_t base = ((size_t)(b*NS))*NK + (size_t)t*48;
    #pragma unroll
    for(int h=0;h<16;h++) Bt[base + h*3] = 0;
  }
  if(s == NS-1){         // zero pad entries: row 63, tap 2
    size_t base = ((size_t)(b*NS+NS-1))*NK + (size_t)t*48 + 2;
    #pragma unroll
    for(int h=0;h<16;h++) Bt[base + h*3] = 0;
  }
}

// ------- k3: GEMM  yp[col][co] = sum_K Bt[col][K] * Bw[co][K] ------------
// M=512, N=4096, K=12288. 128x128 tile, BK=64 (two 32-K sub-buffers per
// operand, each keeping the m97-proven 64-B row stride + gld16-contiguous
// chunk order). Split-K over blockIdx.y; XCD swizzle on blockIdx.x.
__global__ __launch_bounds__(256) void k_gemm(
    const u16* __restrict__ Abt, const u16* __restrict__ Bw,
    float* __restrict__ yp, int kchunk){
  __shared__ __align__(16) u16 As0[128*32];
  __shared__ __align__(16) u16 As1[128*32];
  __shared__ __align__(16) u16 Bs0[128*32];
  __shared__ __align__(16) u16 Bs1[128*32];
  int t = threadIdx.x;
  int id = blockIdx.x;               // 0..127
  int xr_ = id & 7, q0 = id >> 3;    // xcd residue, remainder
  int mI = q0 & 3, nhi = q0 >> 2;    // m in [0,4), nhi in [0,4)
  int m0 = mI*128, n0 = (nhi*8 + xr_)*128;
  int kbeg = blockIdx.y*kchunk;
  f32x4 acc[4][4];
  #pragma unroll
  for(int i=0;i<4;i++)
    #pragma unroll
    for(int j=0;j<4;j++) acc[i][j] = (f32x4){0,0,0,0};

  int l = t&63, w = t>>6;
  int wm = (w&1)*64, wn = (w>>1)*64;
  int q = l>>4, r16 = l&15;

  int c0 = t, c1 = t+256;
  // chunk c: row = c>>2, K-word = c&3 (16B = 8 bf16). hi buffer: +32 K.
  const u16* ga0 = Abt + (size_t)(m0 + (c0>>2))*NK + (c0&3)*8;
  const u16* ga1 = Abt + (size_t)(m0 + (c1>>2))*NK + (c1&3)*8;
  const u16* gb0 = Bw  + (size_t)(n0 + (c0>>2))*NK + (c0&3)*8;
  const u16* gb1 = Bw  + (size_t)(n0 + (c1>>2))*NK + (c1&3)*8;
  u16 *la00 = As0 + c0*8, *la01 = As0 + c1*8;
  u16 *la10 = As1 + c0*8, *la11 = As1 + c1*8;
  u16 *lb00 = Bs0 + c0*8, *lb01 = Bs0 + c1*8;
  u16 *lb10 = Bs1 + c0*8, *lb11 = Bs1 + c1*8;

  for(int kk=0; kk<kchunk; kk+=64){
    int k0 = kbeg + kk;
    __syncthreads();                       // prior iter's LDS reads done
    gld16(la00, ga0 + k0);      gld16(la01, ga1 + k0);
    gld16(lb00, gb0 + k0);      gld16(lb01, gb1 + k0);
    gld16(la10, ga0 + k0 + 32); gld16(la11, ga1 + k0 + 32);
    gld16(lb10, gb0 + k0 + 32); gld16(lb11, gb1 + k0 + 32);
    __syncthreads();                       // drains vmcnt -> staging visible
    {
      bf16x8 af[4], bfr[4];
      #pragma unroll
      for(int mt=0;mt<4;mt++) af[mt]  = *(const bf16x8*)(As0 + (wm+mt*16+r16)*32 + q*8);
      #pragma unroll
      for(int nt=0;nt<4;nt++) bfr[nt] = *(const bf16x8*)(Bs0 + (wn+nt*16+r16)*32 + q*8);
      #pragma unroll
      for(int mt=0;mt<4;mt++)
        #pragma unroll
        for(int nt=0;nt<4;nt++)
          acc[mt][nt] = __builtin_amdgcn_mfma_f32_16x16x32_bf16(af[mt], bfr[nt], acc[mt][nt], 0,0,0);
    }
    {
      bf16x8 af[4], bfr[4];
      #pragma unroll
      for(int mt=0;mt<4;mt++) af[mt]  = *(const bf16x8*)(As1 + (wm+mt*16+r16)*32 + q*8);
      #pragma unroll
      for(int nt=0;nt<4;nt++) bfr[nt] = *(const bf16x8*)(Bs1 + (wn+nt*16+r16)*32 + q*8);
      #pragma unroll
      for(int mt=0;mt<4;mt++)
        #pragma unroll
        for(int nt=0;nt<4;nt++)
          acc[mt][nt] = __builtin_amdgcn_mfma_f32_16x16x32_bf16(af[mt], bfr[nt], acc[mt][nt], 0,0,0);
    }
  }
  float* op = yp + (size_t)blockIdx.y*NP*NC;
  #pragma unroll
  for(int mt=0;mt<4;mt++)
    #pragma unroll
    for(int nt=0;nt<4;nt++)
      #pragma unroll
      for(int rr=0;rr<4;rr++){
        int m = m0 + wm + mt*16 + q*4 + rr;   // C/D: row = quad*4+reg
        int n = n0 + wn + nt*16 + r16;        //      col = lane&15
        op[(size_t)m*NC + n] = acc[mt][nt][rr];
      }
}

// ------ k4: sum split-K, conv_b + BN + relu + residual + LayerNorm -------
__global__ __launch_bounds__(256) void k_post(
    const float* __restrict__ yp, int nparts,
    const float* __restrict__ x,
    const float* __restrict__ cb, const float* __restrict__ bg,
    const float* __restrict__ bb, const float* __restrict__ bm,
    const float* __restrict__ bv, const float* __restrict__ lg,
    const float* __restrict__ lb, float* __restrict__ out){
  int n = threadIdx.x, bs = blockIdx.x;   // bs == col == b*64+s
  float v[16];
  #pragma unroll
  for(int g=0;g<4;g++){
    f32x4 sum = {0,0,0,0};
    for(int p=0;p<nparts;p++)
      sum += ((const f32x4*)(yp + (size_t)p*NP*NC + (size_t)bs*NC + n*16))[g];
    *(f32x4*)&v[g*4] = sum;
  }
  const float* xp = x + ((size_t)bs*NN + n)*NH;
  float xr[16];
  #pragma unroll
  for(int g=0;g<4;g++) *(f32x4*)&xr[g*4] = ((const f32x4*)xp)[g];

  float mu = 0.f;
  #pragma unroll
  for(int h=0;h<16;h++){
    int co = n*16 + h;
    float t1 = v[h] + cb[co];
    t1 = (t1 - bm[co]) * (1.f/sqrtf(bv[co] + EPSV));
    t1 = t1 * bg[co] + bb[co];
    t1 = fmaxf(t1, 0.f);
    t1 += xr[h];
    v[h] = t1; mu += t1;
  }
  mu *= (1.f/16.f);
  float var = 0.f;
  #pragma unroll
  for(int h=0;h<16;h++){ float d = v[h]-mu; var = fmaf(d,d,var); }
  var *= (1.f/16.f);
  float rs = 1.f/sqrtf(var + EPSV);
  float* op = out + ((size_t)bs*NN + n)*NH;
  #pragma unroll
  for(int h=0;h<16;h++) op[h] = (v[h]-mu)*rs*lg[h] + lb[h];
}

extern "C" void kernel_launch(void* const* d_in, const int* in_sizes, int n_in,
                              void* d_out, int out_size, void* d_ws, size_t ws_size,
                              hipStream_t stream){
  const float* x   = (const float*)d_in[0];
  const float* adj = (const float*)d_in[1];
  const float* W   = (const float*)d_in[2];
  const float* a1  = (const float*)d_in[3];
  const float* a2  = (const float*)d_in[4];
  const float* cw  = (const float*)d_in[5];
  const float* cb  = (const float*)d_in[6];
  const float* bg  = (const float*)d_in[7];
  const float* bb  = (const float*)d_in[8];
  const float* bm  = (const float*)d_in[9];
  const float* bv  = (const float*)d_in[10];
  const float* lg  = (const float*)d_in[11];
  const float* lb  = (const float*)d_in[12];
  float* out = (float*)d_out;

  char* ws = (char*)d_ws;
  const size_t AM_OFF = 0;
  const size_t BT_OFF = AM_OFF + (size_t)NN*4*8;
  const size_t BW_OFF = BT_OFF + (size_t)NP*NK*2;      // Bt: 12.6 MB
  const size_t YP_OFF = BW_OFF + (size_t)NC*NK*2;      // Bw: 100.7 MB
  const size_t ypb    = (size_t)NP*NC*4;               // 8 MB per split
  int P = 1;
  if(ws_size >= YP_OFF + 8*ypb)      P = 8;
  else if(ws_size >= YP_OFF + 4*ypb) P = 4;
  else if(ws_size >= YP_OFF + 2*ypb) P = 2;

  u64*   am  = (u64*)  (ws + AM_OFF);
  u16*   Bt  = (u16*)  (ws + BT_OFF);
  u16*   Bw  = (u16*)  (ws + BW_OFF);
  float* yp  = (float*)(ws + YP_OFF);

  hipLaunchKernelGGL(k_adj,  dim3(64),        dim3(256), 0, stream, adj, am);
  hipLaunchKernelGGL(k_cw,   dim3(NC*NK/(256*8)), dim3(256), 0, stream, cw, Bw);
  hipLaunchKernelGGL(k_attn, dim3(NP),        dim3(256), 0, stream, x,W,a1,a2,am,Bt);
  hipLaunchKernelGGL(k_gemm, dim3(128,P),     dim3(256), 0, stream, Bt, Bw, yp, NK/P);
  hipLaunchKernelGGL(k_post, dim3(NP),        dim3(256), 0, stream, yp,P,x,cb,bg,bb,bm,bv,lg,lb,out);
}

// Round 6
// 426.739 us; speedup vs baseline: 1.2887x; 1.1745x over previous
//
#include <hip/hip_runtime.h>
#include <stdint.h>

#define ALPHA 0.2f
#define EPSV  1e-5f

typedef unsigned short u16;
typedef unsigned int   u32;
typedef unsigned long long u64;
typedef __bf16 bf16x8 __attribute__((ext_vector_type(8)));
typedef __bf16 bf16x2 __attribute__((ext_vector_type(2)));
typedef float  f32x4  __attribute__((ext_vector_type(4)));

#define NB 8
#define NS 64
#define NN 256
#define NF 16
#define NH 16
#define NC 4096     // N*H
#define NK 12288    // NC*3
#define NP 512      // B*S (GEMM M / column count)

__device__ __forceinline__ u16 f2b(float f){
  u32 u = __float_as_uint(f);
  u32 r = u + 0x7fffu + ((u>>16)&1u);   // round-nearest-even
  return (u16)(r>>16);
}
__device__ __forceinline__ u32 pack2(float a, float b){ return (u32)f2b(a) | ((u32)f2b(b)<<16); }
__device__ __forceinline__ void un2(u32 v, float& lo, float& hi){
  lo = __uint_as_float(v<<16); hi = __uint_as_float(v & 0xffff0000u);
}
__device__ __forceinline__ void gld16(void* lds, const void* g){
  __builtin_amdgcn_global_load_lds((const __attribute__((address_space(1))) u32*)g,
                                   (__attribute__((address_space(3))) u32*)lds, 16, 0, 0);
}
// 8 fp32 -> 8 bf16 (16B), hoping for v_cvt_pk_bf16_f32 codegen
__device__ __forceinline__ uint4 cvt8(f32x4 a, f32x4 b){
  union { uint4 u; bf16x2 h[4]; } r;
  r.h[0] = (bf16x2){(__bf16)a[0], (__bf16)a[1]};
  r.h[1] = (bf16x2){(__bf16)a[2], (__bf16)a[3]};
  r.h[2] = (bf16x2){(__bf16)b[0], (__bf16)b[1]};
  r.h[3] = (bf16x2){(__bf16)b[2], (__bf16)b[3]};
  return r.u;
}

// ------- k_adj: adjacency -> bitmask, coalesced + ballot (64 blocks) ------
__global__ __launch_bounds__(256) void k_adj(const float* __restrict__ adj,
                                             u64* __restrict__ am){
  int w = threadIdx.x>>6, l = threadIdx.x&63;
  int row = blockIdx.x*4 + w;
  #pragma unroll
  for(int g=0;g<4;g++){
    float v = adj[(size_t)row*NN + g*64 + l];
    u64 m = __ballot(v > 0.f);
    if(l==0) am[row*4+g] = m;
  }
}

// --- k_attn (merged Wh + attention): per block bs, compute Wh rows into
// LDS, then single-pass masked softmax + spatial = attn@Wh -> Bt (bf16).
// Bt[col = b*64+cs][ci*3+k] = t_padded[b][ci][cs+k]  (512 x 12288 bf16)
__global__ __launch_bounds__(256) void k_attn(
    const float* __restrict__ x, const float* __restrict__ W,
    const float* __restrict__ a1, const float* __restrict__ a2,
    const u64* __restrict__ am, u16* __restrict__ Bt){
  __shared__ __align__(16) float Ws[NF][NH];
  __shared__ float a1s[NH], a2s[NH];
  __shared__ __align__(16) float Whs[NN][NH];
  __shared__ float f2s[NN];
  int t = threadIdx.x, bs = blockIdx.x;
  int b = bs>>6, s = bs&63;
  Ws[t>>4][t&15] = W[t];
  if(t<NH){ a1s[t]=a1[t]; a2s[t]=a2[t]; }
  u64 mg[4];
  #pragma unroll
  for(int g=0;g<4;g++) mg[g] = am[t*4+g];
  __syncthreads();

  const float* xp = x + ((size_t)bs*NN + t)*NF;
  float xr[16];
  #pragma unroll
  for(int g=0;g<4;g++) *(f32x4*)&xr[g*4] = ((const f32x4*)xp)[g];
  float wh[16];
  #pragma unroll
  for(int h=0;h<16;h++) wh[h]=0.f;
  #pragma unroll
  for(int f=0;f<16;f++){
    float xf = xr[f];
    #pragma unroll
    for(int h=0;h<16;h++) wh[h] = fmaf(xf, Ws[f][h], wh[h]);
  }
  float fi=0.f, s2=0.f;
  #pragma unroll
  for(int h=0;h<16;h++){ fi=fmaf(wh[h],a1s[h],fi); s2=fmaf(wh[h],a2s[h],s2); }
  #pragma unroll
  for(int g=0;g<4;g++) ((f32x4*)Whs[t])[g] = *(f32x4*)&wh[g*4];
  f2s[t] = s2;
  __syncthreads();

  // single-pass masked softmax (no max-subtract: |e| small in fp32)
  float den = 0.f;
  f32x4 a0={0,0,0,0}, a1v={0,0,0,0}, a2v={0,0,0,0}, a3v={0,0,0,0};
  #pragma unroll
  for(int g=0;g<4;g++){
    u64 mm = mg[g];
    for(int jj=0;jj<64;jj++){
      int j = g*64+jj;
      float e = fi + f2s[j];
      e = e > 0.f ? e : ALPHA*e;
      float p = ((mm>>jj)&1ull) ? __expf(e) : 0.f;
      den += p;
      const f32x4* wr = (const f32x4*)Whs[j];
      a0 += wr[0]*p; a1v += wr[1]*p; a2v += wr[2]*p; a3v += wr[3]*p;
    }
  }
  float inv = 1.f/fmaxf(den, 1e-30f);
  float vals[16];
  *(f32x4*)&vals[0]  = a0*inv;  *(f32x4*)&vals[4]  = a1v*inv;
  *(f32x4*)&vals[8]  = a2v*inv; *(f32x4*)&vals[12] = a3v*inv;

  // scatter: value at source position s contributes to rows cs = s+1-k
  #pragma unroll
  for(int k=0;k<3;k++){
    int cs = s + 1 - k;
    if(cs >= 0 && cs < NS){
      size_t base = ((size_t)(b*NS+cs))*NK + (size_t)t*48 + k;
      #pragma unroll
      for(int h=0;h<16;h++) Bt[base + h*3] = f2b(vals[h]);
    }
  }
  if(s == 0){            // zero pad entries: row 0, tap 0
    size_t base = ((size_t)(b*NS))*NK + (size_t)t*48;
    #pragma unroll
    for(int h=0;h<16;h++) Bt[base + h*3] = 0;
  }
  if(s == NS-1){         // zero pad entries: row 63, tap 2
    size_t base = ((size_t)(b*NS+NS-1))*NK + (size_t)t*48 + 2;
    #pragma unroll
    for(int h=0;h<16;h++) Bt[base + h*3] = 0;
  }
}

// ------- k3: GEMM  yp[col][co] = sum_K Bt[col][K] * conv_w[co][K] --------
// M=512, N=4096, K=12288. 128x128 tile, BK=64 (two 32-K sub-buffers).
// A (Bt, bf16) staged via global_load_lds; B (conv_w, fp32) staged via
// float4 register loads + packed bf16 convert + ds_write_b128 (kills the
// separate 302 MB k_cw pass). Split-K over blockIdx.y; partials in bf16.
__global__ __launch_bounds__(256) void k_gemm(
    const u16* __restrict__ Abt, const float* __restrict__ Bwf,
    u16* __restrict__ yp, int kchunk){
  __shared__ __align__(16) u16 As0[128*32];
  __shared__ __align__(16) u16 As1[128*32];
  __shared__ __align__(16) u16 Bs0[128*32];
  __shared__ __align__(16) u16 Bs1[128*32];
  int t = threadIdx.x;
  int id = blockIdx.x;               // 0..127
  int xr_ = id & 7, q0 = id >> 3;    // xcd residue, remainder
  int mI = q0 & 3, nhi = q0 >> 2;    // m in [0,4), nhi in [0,4)
  int m0 = mI*128, n0 = (nhi*8 + xr_)*128;
  int kbeg = blockIdx.y*kchunk;
  f32x4 acc[4][4];
  #pragma unroll
  for(int i=0;i<4;i++)
    #pragma unroll
    for(int j=0;j<4;j++) acc[i][j] = (f32x4){0,0,0,0};

  int l = t&63, w = t>>6;
  int wm = (w&1)*64, wn = (w>>1)*64;
  int q = l>>4, r16 = l&15;

  int c0 = t, c1 = t+256;
  // chunk c: row = c>>2, K-word = c&3 (8 K-elements). hi buffer: +32 K.
  const u16*   ga0 = Abt + (size_t)(m0 + (c0>>2))*NK + (c0&3)*8;
  const u16*   ga1 = Abt + (size_t)(m0 + (c1>>2))*NK + (c1&3)*8;
  const float* gb0 = Bwf + (size_t)(n0 + (c0>>2))*NK + (c0&3)*8;
  const float* gb1 = Bwf + (size_t)(n0 + (c1>>2))*NK + (c1&3)*8;
  u16 *la00 = As0 + c0*8, *la01 = As0 + c1*8;
  u16 *la10 = As1 + c0*8, *la11 = As1 + c1*8;
  u16 *lb00 = Bs0 + c0*8, *lb01 = Bs0 + c1*8;
  u16 *lb10 = Bs1 + c0*8, *lb11 = Bs1 + c1*8;

  for(int kk=0; kk<kchunk; kk+=64){
    int k0 = kbeg + kk;
    // B tile: fp32 register loads (8 x float4), convert to bf16
    f32x4 v00a = *(const f32x4*)(gb0 + k0);
    f32x4 v00b = *(const f32x4*)(gb0 + k0 + 4);
    f32x4 v01a = *(const f32x4*)(gb1 + k0);
    f32x4 v01b = *(const f32x4*)(gb1 + k0 + 4);
    f32x4 v10a = *(const f32x4*)(gb0 + k0 + 32);
    f32x4 v10b = *(const f32x4*)(gb0 + k0 + 36);
    f32x4 v11a = *(const f32x4*)(gb1 + k0 + 32);
    f32x4 v11b = *(const f32x4*)(gb1 + k0 + 36);
    uint4 w00 = cvt8(v00a, v00b);
    uint4 w01 = cvt8(v01a, v01b);
    uint4 w10 = cvt8(v10a, v10b);
    uint4 w11 = cvt8(v11a, v11b);
    __syncthreads();                       // prior iter's LDS reads done
    gld16(la00, ga0 + k0);      gld16(la01, ga1 + k0);
    gld16(la10, ga0 + k0 + 32); gld16(la11, ga1 + k0 + 32);
    *(uint4*)lb00 = w00; *(uint4*)lb01 = w01;
    *(uint4*)lb10 = w10; *(uint4*)lb11 = w11;
    __syncthreads();                       // staging visible to all waves
    {
      bf16x8 af[4], bfr[4];
      #pragma unroll
      for(int mt=0;mt<4;mt++) af[mt]  = *(const bf16x8*)(As0 + (wm+mt*16+r16)*32 + q*8);
      #pragma unroll
      for(int nt=0;nt<4;nt++) bfr[nt] = *(const bf16x8*)(Bs0 + (wn+nt*16+r16)*32 + q*8);
      #pragma unroll
      for(int mt=0;mt<4;mt++)
        #pragma unroll
        for(int nt=0;nt<4;nt++)
          acc[mt][nt] = __builtin_amdgcn_mfma_f32_16x16x32_bf16(af[mt], bfr[nt], acc[mt][nt], 0,0,0);
    }
    {
      bf16x8 af[4], bfr[4];
      #pragma unroll
      for(int mt=0;mt<4;mt++) af[mt]  = *(const bf16x8*)(As1 + (wm+mt*16+r16)*32 + q*8);
      #pragma unroll
      for(int nt=0;nt<4;nt++) bfr[nt] = *(const bf16x8*)(Bs1 + (wn+nt*16+r16)*32 + q*8);
      #pragma unroll
      for(int mt=0;mt<4;mt++)
        #pragma unroll
        for(int nt=0;nt<4;nt++)
          acc[mt][nt] = __builtin_amdgcn_mfma_f32_16x16x32_bf16(af[mt], bfr[nt], acc[mt][nt], 0,0,0);
    }
  }
  u16* op = yp + (size_t)blockIdx.y*NP*NC;
  #pragma unroll
  for(int mt=0;mt<4;mt++)
    #pragma unroll
    for(int nt=0;nt<4;nt++)
      #pragma unroll
      for(int rr=0;rr<4;rr++){
        int m = m0 + wm + mt*16 + q*4 + rr;   // C/D: row = quad*4+reg
        int n = n0 + wn + nt*16 + r16;        //      col = lane&15
        op[(size_t)m*NC + n] = f2b(acc[mt][nt][rr]);
      }
}

// ------ k4: sum split-K (bf16), conv_b+BN+relu+residual+LayerNorm --------
__global__ __launch_bounds__(256) void k_post(
    const u16* __restrict__ yp, int nparts,
    const float* __restrict__ x,
    const float* __restrict__ cb, const float* __restrict__ bg,
    const float* __restrict__ bb, const float* __restrict__ bm,
    const float* __restrict__ bv, const float* __restrict__ lg,
    const float* __restrict__ lb, float* __restrict__ out){
  int n = threadIdx.x, bs = blockIdx.x;   // bs == col == b*64+s
  float v[16];
  #pragma unroll
  for(int h=0;h<16;h++) v[h]=0.f;
  for(int p=0;p<nparts;p++){
    const u16* pp = yp + (size_t)p*NP*NC + (size_t)bs*NC + n*16;
    uint4 u0 = ((const uint4*)pp)[0];
    uint4 u1 = ((const uint4*)pp)[1];
    float lo, hi;
    un2(u0.x,lo,hi); v[0]+=lo;  v[1]+=hi;
    un2(u0.y,lo,hi); v[2]+=lo;  v[3]+=hi;
    un2(u0.z,lo,hi); v[4]+=lo;  v[5]+=hi;
    un2(u0.w,lo,hi); v[6]+=lo;  v[7]+=hi;
    un2(u1.x,lo,hi); v[8]+=lo;  v[9]+=hi;
    un2(u1.y,lo,hi); v[10]+=lo; v[11]+=hi;
    un2(u1.z,lo,hi); v[12]+=lo; v[13]+=hi;
    un2(u1.w,lo,hi); v[14]+=lo; v[15]+=hi;
  }
  const float* xp = x + ((size_t)bs*NN + n)*NH;
  float xr[16];
  #pragma unroll
  for(int g=0;g<4;g++) *(f32x4*)&xr[g*4] = ((const f32x4*)xp)[g];

  float mu = 0.f;
  #pragma unroll
  for(int h=0;h<16;h++){
    int co = n*16 + h;
    float t1 = v[h] + cb[co];
    t1 = (t1 - bm[co]) * (1.f/sqrtf(bv[co] + EPSV));
    t1 = t1 * bg[co] + bb[co];
    t1 = fmaxf(t1, 0.f);
    t1 += xr[h];
    v[h] = t1; mu += t1;
  }
  mu *= (1.f/16.f);
  float var = 0.f;
  #pragma unroll
  for(int h=0;h<16;h++){ float d = v[h]-mu; var = fmaf(d,d,var); }
  var *= (1.f/16.f);
  float rs = 1.f/sqrtf(var + EPSV);
  float* op = out + ((size_t)bs*NN + n)*NH;
  #pragma unroll
  for(int h=0;h<16;h++) op[h] = (v[h]-mu)*rs*lg[h] + lb[h];
}

extern "C" void kernel_launch(void* const* d_in, const int* in_sizes, int n_in,
                              void* d_out, int out_size, void* d_ws, size_t ws_size,
                              hipStream_t stream){
  const float* x   = (const float*)d_in[0];
  const float* adj = (const float*)d_in[1];
  const float* W   = (const float*)d_in[2];
  const float* a1  = (const float*)d_in[3];
  const float* a2  = (const float*)d_in[4];
  const float* cw  = (const float*)d_in[5];
  const float* cb  = (const float*)d_in[6];
  const float* bg  = (const float*)d_in[7];
  const float* bb  = (const float*)d_in[8];
  const float* bm  = (const float*)d_in[9];
  const float* bv  = (const float*)d_in[10];
  const float* lg  = (const float*)d_in[11];
  const float* lb  = (const float*)d_in[12];
  float* out = (float*)d_out;

  char* ws = (char*)d_ws;
  const size_t AM_OFF = 0;
  const size_t BT_OFF = AM_OFF + (size_t)NN*4*8;
  const size_t YP_OFF = BT_OFF + (size_t)NP*NK*2;      // Bt: 12.6 MB
  const size_t ypb    = (size_t)NP*NC*2;               // 4 MB per split (bf16)
  int P = 1;
  if(ws_size >= YP_OFF + 8*ypb)      P = 8;
  else if(ws_size >= YP_OFF + 4*ypb) P = 4;
  else if(ws_size >= YP_OFF + 2*ypb) P = 2;

  u64*   am  = (u64*)  (ws + AM_OFF);
  u16*   Bt  = (u16*)  (ws + BT_OFF);
  u16*   yp  = (u16*)  (ws + YP_OFF);

  hipLaunchKernelGGL(k_adj,  dim3(64),    dim3(256), 0, stream, adj, am);
  hipLaunchKernelGGL(k_attn, dim3(NP),    dim3(256), 0, stream, x,W,a1,a2,am,Bt);
  hipLaunchKernelGGL(k_gemm, dim3(128,P), dim3(256), 0, stream, Bt, cw, yp, NK/P);
  hipLaunchKernelGGL(k_post, dim3(NP),    dim3(256), 0, stream, yp,P,x,cb,bg,bb,bm,bv,lg,lb,out);
}